// Round 11
// baseline (163.717 us; speedup 1.0000x reference)
//
#include <hip/hip_runtime.h>
#include <hip/hip_bf16.h>

// Shapes (fixed for this problem)
#define S_LEN 1024
#define D_DIM 1024
#define N_BAT 8
#define BSS   (8ull*1024ull*1024ull)   // B*S*S elements per output

using bf16x8 = __attribute__((ext_vector_type(8))) short;
using f32x4  = __attribute__((ext_vector_type(4))) float;

__device__ __forceinline__ short f2bf(float v) {
    __hip_bfloat16 h = __float2bfloat16(v);
    return *reinterpret_cast<short*>(&h);
}

__device__ __forceinline__ void gload_lds16(const void* g, void* l) {
    __builtin_amdgcn_global_load_lds(
        (const __attribute__((address_space(1))) void*)g,
        (__attribute__((address_space(3))) void*)l, 16, 0, 0);
}

// ---------------------------------------------------------------------------
// m201-style 8-phase 256x256 GEMM mainloop. BK=64, 16 K-tiles (K=1024).
// 8 waves (512 thr) as 2M x 4N -> wave tile 128x64, acc[8][4] f32x4.
// LDS: A,B each 2 x 32KB double-buffer (128 KB). Each K-tile = 4 halves
// (A-h0, A-h1, B-h0, B-h1; 16 KB each, 2 gload_lds16/thread).
// Per K-tile, 4 phases (C-quadrants 00,01,11,10):
//   phase: stage one half of tile t+1 | ds_read one operand half |
//          barrier | MFMA cluster (16) in setprio(1) | barrier
// vmcnt(2) ONCE per K-tile (phase 0): tile t fully landed, t+1-h0 in flight.
// XOR swizzle byte^((row&7)<<4): pre-swizzled global src, same XOR on read
// (verified 0 bank conflicts R6-R10).
// ---------------------------------------------------------------------------
#define RD_A(dst, bufb, MH)                                                  \
    {                                                                        \
        const char* _b = (const char*)As + (bufb);                           \
        _Pragma("unroll")                                                    \
        for (int _m = 0; _m < 4; ++_m) {                                     \
            const int _row = wr * 128 + ((MH) * 4 + _m) * 16 + rsel;         \
            const int _sw  = (_row & 7) << 4;                                \
            _Pragma("unroll")                                                \
            for (int _kk = 0; _kk < 2; ++_kk)                                \
                dst[_m * 2 + _kk] = *(const bf16x8*)&_b[_row * 128 +         \
                                        ((_kk * 64 + kb) ^ _sw)];            \
        }                                                                    \
    }

#define RD_B(dst, bufb, NH)                                                  \
    {                                                                        \
        const char* _b = (const char*)Bs + (bufb);                           \
        _Pragma("unroll")                                                    \
        for (int _n = 0; _n < 2; ++_n) {                                     \
            const int _row = wc * 64 + ((NH) * 2 + _n) * 16 + rsel;          \
            const int _sw  = (_row & 7) << 4;                                \
            _Pragma("unroll")                                                \
            for (int _kk = 0; _kk < 2; ++_kk)                                \
                dst[_n * 2 + _kk] = *(const bf16x8*)&_b[_row * 128 +         \
                                        ((_kk * 64 + kb) ^ _sw)];            \
        }                                                                    \
    }

#define MMA_Q(av, bv, MH, NH)                                                \
    __builtin_amdgcn_s_setprio(1);                                           \
    _Pragma("unroll")                                                        \
    for (int _kk = 0; _kk < 2; ++_kk)                                        \
        _Pragma("unroll")                                                    \
        for (int _m = 0; _m < 4; ++_m)                                       \
            _Pragma("unroll")                                                \
            for (int _n = 0; _n < 2; ++_n)                                   \
                acc[(MH) * 4 + _m][(NH) * 2 + _n] =                          \
                    __builtin_amdgcn_mfma_f32_16x16x32_bf16(                 \
                        av[_m * 2 + _kk], bv[_n * 2 + _kk],                  \
                        acc[(MH) * 4 + _m][(NH) * 2 + _n], 0, 0, 0);         \
    __builtin_amdgcn_s_setprio(0);

#define PHASE_END()                                                          \
    __builtin_amdgcn_s_barrier();                                            \
    __builtin_amdgcn_sched_barrier(0);

template<int KTILES>
__device__ __forceinline__ void gemm_ml_8ph(
    const short* __restrict__ A, const short* __restrict__ Bt,
    int brow, int bcol, int kstart,
    short* As, short* Bs, f32x4 acc[8][4])
{
    const int tid  = threadIdx.x;
    const int lane = tid & 63;
    const int w    = tid >> 6;
    const int wr   = w >> 2;            // 0..1  (M half, 128 rows)
    const int wc   = w & 3;             // 0..3  (N quarter, 64 cols)
    const int rsel = lane & 15;
    const int kb   = (lane >> 4) * 16;

    // staging map: flat f in [0,1024) covers one 128-row half (16 KB)
    const int f0 = tid;
    const int f1 = 512 + tid;
    const int r0 = f0 >> 3, cb0 = ((f0 & 7) * 16) ^ ((r0 & 7) << 4);
    const int r1 = f1 >> 3, cb1 = ((f1 & 7) * 16) ^ ((r1 & 7) << 4);

#pragma unroll
    for (int m = 0; m < 8; ++m)
#pragma unroll
        for (int n = 0; n < 4; ++n) acc[m][n] = 0.0f;

    auto stageA = [&](int buf, int h, int k0) {
        char* d = (char*)As + buf * 32768 + h * 16384;
        gload_lds16((const char*)(A + (size_t)(brow + h * 128 + r0) * 1024 + k0) + cb0,
                    d + f0 * 16);
        gload_lds16((const char*)(A + (size_t)(brow + h * 128 + r1) * 1024 + k0) + cb1,
                    d + f1 * 16);
    };
    auto stageB = [&](int buf, int h, int k0) {
        char* d = (char*)Bs + buf * 32768 + h * 16384;
        gload_lds16((const char*)(Bt + (size_t)(bcol + h * 128 + r0) * 1024 + k0) + cb0,
                    d + f0 * 16);
        gload_lds16((const char*)(Bt + (size_t)(bcol + h * 128 + r1) * 1024 + k0) + cb1,
                    d + f1 * 16);
    };

    // prologue: full tile 0
    stageA(0, 0, kstart); stageA(0, 1, kstart);
    stageB(0, 0, kstart); stageB(0, 1, kstart);

    bf16x8 a[8], b0[4], b1[4];
    for (int t = 0; t < KTILES; ++t) {
        const int cur = t & 1, nxt = cur ^ 1;
        const int curb = cur * 32768;
        const int kn = kstart + (t + 1) * 64;
        const bool pre = (t + 1 < KTILES);
        // ---- phase 0: quadrant (0,0) ----
        if (pre) {
            stageA(nxt, 0, kn);
            asm volatile("s_waitcnt vmcnt(2)" ::: "memory");
        } else {
            asm volatile("s_waitcnt vmcnt(0)" ::: "memory");
        }
        __builtin_amdgcn_s_barrier();
        __builtin_amdgcn_sched_barrier(0);
        RD_A(a, curb, 0);
        RD_B(b0, curb, 0);
        MMA_Q(a, b0, 0, 0);
        PHASE_END();
        // ---- phase 1: quadrant (0,1) ----
        if (pre) stageA(nxt, 1, kn);
        RD_B(b1, curb, 1);
        MMA_Q(a, b1, 0, 1);
        PHASE_END();
        // ---- phase 2: quadrant (1,1) ----
        if (pre) stageB(nxt, 0, kn);
        RD_A(a, curb, 1);
        MMA_Q(a, b1, 1, 1);
        PHASE_END();
        // ---- phase 3: quadrant (1,0) ----
        if (pre) stageB(nxt, 1, kn);
        MMA_Q(a, b0, 1, 0);
        PHASE_END();
    }
}

// ---------------------------------------------------------------------------
// 3a) bf16-out GEMM for t = xb @ m2t^T. Grid (32,4) = 128 blocks of 256^2.
//     XCD map: 4 contiguous M-panels x all cols per XCD (2MB+2MB in L2).
// ---------------------------------------------------------------------------
__global__ __launch_bounds__(512, 2) void gemm_bf16(
    const short* __restrict__ A, const short* __restrict__ Bt,
    short* __restrict__ C)
{
    __shared__ short As[2 * 16384];
    __shared__ short Bs[2 * 16384];
    const int flat = blockIdx.x + 32 * blockIdx.y;
    const int nid  = (flat & 7) * 16 + (flat >> 3);
    const int mx   = nid >> 2;          // 0..31
    const int ny   = nid & 3;           // 0..3
    const int brow = mx * 256, bcol = ny * 256;

    f32x4 acc[8][4];
    gemm_ml_8ph<16>(A, Bt, brow, bcol, 0, As, Bs, acc);

    const int lane = threadIdx.x & 63;
    const int w    = threadIdx.x >> 6;
    const int wr   = w >> 2, wc = w & 3;
#pragma unroll
    for (int mm = 0; mm < 8; ++mm)
#pragma unroll
        for (int nn = 0; nn < 4; ++nn) {
            const int colg = bcol + wc * 64 + nn * 16 + (lane & 15);
#pragma unroll
            for (int r = 0; r < 4; ++r) {
                const int rowg = brow + wr * 128 + mm * 16 + ((lane >> 4) * 4 + r);
                C[(size_t)rowg * 1024 + colg] = f2bf(acc[mm][nn][r]);
            }
        }
}

// ---------------------------------------------------------------------------
// 3b) Scores GEMM + mask epilogue. Grid (4,4,8) = 128 blocks of 256^2;
//     one batch per XCD (t+x slices = 4MB in L2).
// ---------------------------------------------------------------------------
__global__ __launch_bounds__(512, 2) void gemm_scores(
    const short* __restrict__ Tm, const short* __restrict__ Xm,
    const float* __restrict__ p, const float* __restrict__ r2,
    const float* __restrict__ c0p, const int* __restrict__ adj,
    float* __restrict__ Sc)
{
    __shared__ short As[2 * 16384];
    __shared__ short Bs[2 * 16384];
    const int flat = blockIdx.x + 4 * blockIdx.y + 16 * blockIdx.z;
    const int nid  = (flat & 7) * 16 + (flat >> 3);
    const int b    = nid >> 4;
    const int rem  = nid & 15;
    const int mx   = rem & 3;
    const int ny   = rem >> 2;
    const short* A  = Tm + (size_t)b * 1024 * 1024;
    const short* Bt = Xm + (size_t)b * 1024 * 1024;
    const float* pb = p  + (size_t)b * 1024;
    const float* rb = r2 + (size_t)b * 1024;
    const int*   ab = adj + (size_t)b * 1024 * 1024;
    float* C = Sc + (size_t)b * 1024 * 1024;
    const int brow = mx * 256, bcol = ny * 256;

    f32x4 acc[8][4];
    gemm_ml_8ph<16>(A, Bt, brow, bcol, 0, As, Bs, acc);

    const int lane = threadIdx.x & 63;
    const int w    = threadIdx.x >> 6;
    const int wr   = w >> 2, wc = w & 3;
    const float c0v = c0p[0];
#pragma unroll
    for (int mm = 0; mm < 8; ++mm)
#pragma unroll
        for (int nn = 0; nn < 4; ++nn) {
            const int colg = bcol + wc * 64 + nn * 16 + (lane & 15);
            const float radd = rb[colg] + c0v;
#pragma unroll
            for (int r = 0; r < 4; ++r) {
                const int rowg = brow + wr * 128 + mm * 16 + ((lane >> 4) * 4 + r);
                const size_t idx = (size_t)rowg * 1024 + colg;
                const float val = (acc[mm][nn][r] + pb[rowg] + radd) * 0.001953125f;
                C[idx] = ab[idx] ? val : -1e9f;
            }
        }
}

// ---------------------------------------------------------------------------
// 3c) M2T split-K GEMM: grid (4,2,4): 256^2 tiles (mx, ny in 0..3 via
//     packing), z = K-quarter, KTILES=4. 32 blocks... use (4,4,4)? N=1024
//     -> 4 col tiles. Grid (4,4,4) = 64 blocks.
// ---------------------------------------------------------------------------
__global__ __launch_bounds__(512, 2) void gemm_splitk(
    const short* __restrict__ A, const short* __restrict__ Bt,
    float* __restrict__ P)
{
    __shared__ short As[2 * 16384];
    __shared__ short Bs[2 * 16384];
    const int brow = blockIdx.x * 256, bcol = blockIdx.y * 256;
    const int z = blockIdx.z;

    f32x4 acc[8][4];
    gemm_ml_8ph<4>(A, Bt, brow, bcol, z * 256, As, Bs, acc);

    float* Pz = P + (size_t)z * 1024 * 1024;
    const int lane = threadIdx.x & 63;
    const int w    = threadIdx.x >> 6;
    const int wr   = w >> 2, wc = w & 3;
#pragma unroll
    for (int mm = 0; mm < 8; ++mm)
#pragma unroll
        for (int nn = 0; nn < 4; ++nn) {
            const int colg = bcol + wc * 64 + nn * 16 + (lane & 15);
#pragma unroll
            for (int r = 0; r < 4; ++r) {
                const int rowg = brow + wr * 128 + mm * 16 + ((lane >> 4) * 4 + r);
                Pz[(size_t)rowg * 1024 + colg] = acc[mm][nn][r];
            }
        }
}

// ---------------------------------------------------------------------------
// 3d) Reduce split-K partials -> bf16 m2t
// ---------------------------------------------------------------------------
__global__ __launch_bounds__(256) void reduce_m2t(
    const float* __restrict__ P, short* __restrict__ M)
{
    const int idx = blockIdx.x * 256 + threadIdx.x;
    const float4* P4 = (const float4*)P;
    float4 s = P4[idx];
    const float4 s1 = P4[idx + 262144];
    const float4 s2 = P4[idx + 524288];
    const float4 s3 = P4[idx + 786432];
    s.x += s1.x + s2.x + s3.x;
    s.y += s1.y + s2.y + s3.y;
    s.z += s1.z + s2.z + s3.z;
    s.w += s1.w + s2.w + s3.w;
    short4 o;
    o.x = f2bf(s.x); o.y = f2bf(s.y); o.z = f2bf(s.z); o.w = f2bf(s.w);
    ((short4*)M)[idx] = o;
}

// ---------------------------------------------------------------------------
// 0a/0b) Bias GEMV (unchanged)
// ---------------------------------------------------------------------------
__global__ __launch_bounds__(256) void bias_gemv1(
    const float* __restrict__ Wq, const float* __restrict__ Wk,
    const float* __restrict__ bk, const float* __restrict__ bq,
    float* __restrict__ pu, float* __restrict__ pv)
{
    __shared__ float su[8][128];
    __shared__ float sv[8][128];
    const int tx = threadIdx.x & 31;
    const int ty = threadIdx.x >> 5;
    const int colBase = blockIdx.x * 128;
    const int rowBase = blockIdx.y * 64;
    const int i = colBase + tx * 4;
    float4 au = {0,0,0,0}, av = {0,0,0,0};
#pragma unroll
    for (int jj = 0; jj < 8; ++jj) {
        const int j = rowBase + ty + jj * 8;
        const float bkv = bk[j], bqv = bq[j];
        const float4 wq = *(const float4*)&Wq[(size_t)j * 1024 + i];
        const float4 wk = *(const float4*)&Wk[(size_t)j * 1024 + i];
        au.x += wq.x * bkv; au.y += wq.y * bkv; au.z += wq.z * bkv; au.w += wq.w * bkv;
        av.x += wk.x * bqv; av.y += wk.y * bqv; av.z += wk.z * bqv; av.w += wk.w * bqv;
    }
    ((float4*)su[ty])[tx] = au;
    ((float4*)sv[ty])[tx] = av;
    __syncthreads();
    if (ty == 0) {
        float4 s1 = ((float4*)su[0])[tx];
        float4 s2 = ((float4*)sv[0])[tx];
#pragma unroll
        for (int k = 1; k < 8; ++k) {
            const float4 t1 = ((float4*)su[k])[tx];
            const float4 t2 = ((float4*)sv[k])[tx];
            s1.x += t1.x; s1.y += t1.y; s1.z += t1.z; s1.w += t1.w;
            s2.x += t2.x; s2.y += t2.y; s2.z += t2.z; s2.w += t2.w;
        }
        ((float4*)&pu[(size_t)blockIdx.y * 1024 + colBase])[tx] = s1;
        ((float4*)&pv[(size_t)blockIdx.y * 1024 + colBase])[tx] = s2;
    }
}

__global__ __launch_bounds__(256) void bias_gemv2(
    const float* __restrict__ pu, const float* __restrict__ pv,
    const float* __restrict__ bk, const float* __restrict__ bq,
    float* __restrict__ u, float* __restrict__ v, float* __restrict__ c0)
{
    __shared__ float sh[4];
    const int i = blockIdx.x * 256 + threadIdx.x;
    float su = 0.0f, sv = 0.0f;
#pragma unroll
    for (int k = 0; k < 16; ++k) {
        su += pu[k * 1024 + i];
        sv += pv[k * 1024 + i];
    }
    u[i] = su;
    v[i] = sv;
    if (blockIdx.x == 0) {
        const int t = threadIdx.x;
        const float4 a = ((const float4*)bq)[t];
        const float4 b = ((const float4*)bk)[t];
        float s = a.x*b.x + a.y*b.y + a.z*b.z + a.w*b.w;
        for (int off = 32; off > 0; off >>= 1) s += __shfl_down(s, off);
        const int lane = t & 63, w = t >> 6;
        if (lane == 0) sh[w] = s;
        __syncthreads();
        if (t == 0) c0[0] = sh[0] + sh[1] + sh[2] + sh[3];
    }
}

// ---------------------------------------------------------------------------
// 1) LayerNorm -> bf16 (unchanged)
// ---------------------------------------------------------------------------
__global__ __launch_bounds__(256) void ln_kernel(
    const float* __restrict__ X, const float* __restrict__ gamma,
    const float* __restrict__ beta, const float* __restrict__ u,
    const float* __restrict__ v2, short* __restrict__ Y,
    float* __restrict__ p, float* __restrict__ r2)
{
    __shared__ float sh[16];
    const size_t row = blockIdx.x;
    const int t = threadIdx.x;
    float4 v = ((const float4*)(X + row * 1024))[t];
    float s  = v.x + v.y + v.z + v.w;
    float ss = v.x*v.x + v.y*v.y + v.z*v.z + v.w*v.w;
    for (int off = 32; off > 0; off >>= 1) {
        s  += __shfl_down(s, off);
        ss += __shfl_down(ss, off);
    }
    const int lane = t & 63, w = t >> 6;
    if (lane == 0) { sh[w] = s; sh[4 + w] = ss; }
    __syncthreads();
    if (t == 0) {
        float S  = sh[0] + sh[1] + sh[2] + sh[3];
        float SS = sh[4] + sh[5] + sh[6] + sh[7];
        float mu = S * (1.0f / 1024.0f);
        float var = fmaxf((SS - S * mu) * (1.0f / 1023.0f), 0.0f);
        sh[0] = mu;
        sh[1] = 1.0f / (sqrtf(var) + 1e-6f);
    }
    __syncthreads();
    const float mu = sh[0], inv = sh[1];
    float4 g  = ((const float4*)gamma)[t];
    float4 be = ((const float4*)beta)[t];
    float y0 = g.x * (v.x - mu) * inv + be.x;
    float y1 = g.y * (v.y - mu) * inv + be.y;
    float y2 = g.z * (v.z - mu) * inv + be.z;
    float y3 = g.w * (v.w - mu) * inv + be.w;
    short4 o;
    o.x = f2bf(y0); o.y = f2bf(y1); o.z = f2bf(y2); o.w = f2bf(y3);
    ((short4*)(Y + row * 1024))[t] = o;
    float4 uu = ((const float4*)u)[t];
    float4 vv = ((const float4*)v2)[t];
    float dp = y0*uu.x + y1*uu.y + y2*uu.z + y3*uu.w;
    float dr = y0*vv.x + y1*vv.y + y2*vv.z + y3*vv.w;
    for (int off = 32; off > 0; off >>= 1) {
        dp += __shfl_down(dp, off);
        dr += __shfl_down(dr, off);
    }
    if (lane == 0) { sh[8 + w] = dp; sh[12 + w] = dr; }
    __syncthreads();
    if (t == 0) {
        p[row]  = sh[8] + sh[9] + sh[10] + sh[11];
        r2[row] = sh[12] + sh[13] + sh[14] + sh[15];
    }
}

// ---------------------------------------------------------------------------
// 2) Transpose + convert Wq, Wk -> bf16 transposed copies (unchanged)
// ---------------------------------------------------------------------------
__global__ __launch_bounds__(256) void cvt_t_kernel(
    const float* __restrict__ Wq, const float* __restrict__ Wk,
    short* __restrict__ wqt, short* __restrict__ wkt)
{
    __shared__ float T[32][33];
    const float* src = blockIdx.z ? Wk : Wq;
    short* dst = blockIdx.z ? wkt : wqt;
    const int bi = blockIdx.x * 32, bj = blockIdx.y * 32;
    const int c = threadIdx.x & 31, r0 = threadIdx.x >> 5;
#pragma unroll
    for (int rr = 0; rr < 4; ++rr) {
        const int r = r0 + rr * 8;
        T[r][c] = src[(size_t)(bi + r) * 1024 + bj + c];
    }
    __syncthreads();
#pragma unroll
    for (int rr = 0; rr < 4; ++rr) {
        const int r = r0 + rr * 8;
        dst[(size_t)(bj + r) * 1024 + bi + c] = f2bf(T[c][r]);
    }
}

// ---------------------------------------------------------------------------
// 5) Row stats: M = rowmax(masked scores), inv = 1/sum(exp(sc-M)).
// ---------------------------------------------------------------------------
__global__ __launch_bounds__(256) void rowstat_kernel(
    const float* __restrict__ Sc, float2* __restrict__ stats)
{
    __shared__ float sh[4];
    const size_t row = blockIdx.x;
    const int t = threadIdx.x;
    const float4 sv = ((const float4*)(Sc + row * 1024))[t];
    float m = fmaxf(fmaxf(sv.x, sv.y), fmaxf(sv.z, sv.w));
    for (int off = 32; off > 0; off >>= 1) m = fmaxf(m, __shfl_down(m, off));
    const int lane = t & 63, w = t >> 6;
    if (lane == 0) sh[w] = m;
    __syncthreads();
    const float M = fmaxf(fmaxf(sh[0], sh[1]), fmaxf(sh[2], sh[3]));
    __syncthreads();
    float s = expf(sv.x - M) + expf(sv.y - M) + expf(sv.z - M) + expf(sv.w - M);
    for (int off = 32; off > 0; off >>= 1) s += __shfl_down(s, off);
    if (lane == 0) sh[w] = s;
    __syncthreads();
    if (t == 0) {
        const float Sm = sh[0] + sh[1] + sh[2] + sh[3];
        stats[row] = make_float2(M, 1.0f / Sm);
    }
}

// ---------------------------------------------------------------------------
// 6) Prefix sums of L[k]=log(na[k,k+1]+1e-9) per batch (f64 scan in LDS)
// ---------------------------------------------------------------------------
__global__ __launch_bounds__(1024) void cum2_kernel(
    const float* __restrict__ Sc, const float2* __restrict__ stats,
    const float* __restrict__ prior_p, double* __restrict__ cum)
{
    __shared__ double sh[1024];
    const int b = blockIdx.x;
    const int t = threadIdx.x;
    const float prior = *prior_p;
    const float om = 1.0f - prior;
    const float* sc = Sc + (size_t)b * 1024 * 1024;
    const float2* st = stats + (size_t)b * 1024;
    double v = 0.0;
    if (t >= 1) {
        const int k = t - 1;
        const float2 s1 = st[k], s2 = st[k + 1];
        const float a1 = expf(sc[(size_t)k * 1024 + (k + 1)] - s1.x) * s1.y;
        const float a2 = expf(sc[(size_t)(k + 1) * 1024 + k] - s2.x) * s2.y;
        const float na = prior + om * sqrtf(a1 * a2 + 1e-9f);
        v = (double)logf(na + 1e-9f);
    }
    sh[t] = v;
    __syncthreads();
#pragma unroll
    for (int off = 1; off < 1024; off <<= 1) {
        const double add = (t >= off) ? sh[t - off] : 0.0;
        __syncthreads();
        sh[t] += add;
        __syncthreads();
    }
    cum[b * 1024 + t] = sh[t];
}

// ---------------------------------------------------------------------------
// 7) Fused softmax-finish + na + g fill (unchanged from R10)
// ---------------------------------------------------------------------------
__global__ __launch_bounds__(256) void na_g2_kernel(
    float* __restrict__ Sc, const float2* __restrict__ stats,
    const float* __restrict__ prior_p, const double* __restrict__ cum,
    float* __restrict__ NA)
{
    const int flat = blockIdx.x + 1024 * blockIdx.y;
    const int nid  = (flat & 7) * 1024 + (flat >> 3);
    const int b    = nid >> 10;
    const int tidx = nid & 1023;
    const int ti = tidx >> 5, tj = tidx & 31;
    if (tj < ti) return;
    const float prior = *prior_p;
    const float om = 1.0f - prior;
    float* sc = Sc + (size_t)b * 1024 * 1024;
    float* na = NA + (size_t)b * 1024 * 1024;
    const float2* st = stats + (size_t)b * 1024;
    const double* cb = cum + (size_t)b * 1024;
    __shared__ float T1[32][33];
    __shared__ float T2[32][33];
    const int c = threadIdx.x & 31, r0 = threadIdx.x >> 5;
#pragma unroll
    for (int rr = 0; rr < 4; ++rr) {
        const int r = r0 + rr * 8;
        const int R1 = ti * 32 + r, R2 = tj * 32 + r;
        const float2 s1 = st[R1], s2 = st[R2];
        T1[r][c] = expf(sc[(size_t)R1 * 1024 + tj * 32 + c] - s1.x) * s1.y;
        T2[r][c] = expf(sc[(size_t)R2 * 1024 + ti * 32 + c] - s2.x) * s2.y;
    }
    __syncthreads();
#pragma unroll
    for (int rr = 0; rr < 4; ++rr) {
        const int r = r0 + rr * 8;
        const int R1 = ti * 32 + r, C1 = tj * 32 + c;
        const float na1 = prior + om * sqrtf(T1[r][c] * T2[c][r] + 1e-9f);
        na[(size_t)R1 * 1024 + C1] = na1;
        float g1;
        if (R1 == C1) g1 = na1;
        else {
            const int lo = min(R1, C1), hi = max(R1, C1);
            g1 = expf((float)(cb[hi] - cb[lo])) + 1e-9f;
        }
        sc[(size_t)R1 * 1024 + C1] = g1;
        const int R2 = tj * 32 + r, C2 = ti * 32 + c;
        const float na2 = prior + om * sqrtf(T2[r][c] * T1[c][r] + 1e-9f);
        na[(size_t)R2 * 1024 + C2] = na2;
        float g2;
        if (R2 == C2) g2 = na2;
        else {
            const int lo = min(R2, C2), hi = max(R2, C2);
            g2 = expf((float)(cb[hi] - cb[lo])) + 1e-9f;
        }
        sc[(size_t)R2 * 1024 + C2] = g2;
    }
}

// ---------------------------------------------------------------------------
extern "C" void kernel_launch(void* const* d_in, const int* in_sizes, int n_in,
                              void* d_out, int out_size, void* d_ws, size_t ws_size,
                              hipStream_t stream)
{
    const float* context = (const float*)d_in[0];
    // d_in[1] = eos_mask (unused by reference)
    const float* prior   = (const float*)d_in[2];
    const int*   adj     = (const int*)d_in[3];
    const float* Wk      = (const float*)d_in[4];
    const float* bk      = (const float*)d_in[5];
    const float* Wq      = (const float*)d_in[6];
    const float* bq      = (const float*)d_in[7];
    const float* gamma   = (const float*)d_in[8];
    const float* beta    = (const float*)d_in[9];

    float* out   = (float*)d_out;
    float* gout  = out;          // g_attn output (holds masked scores first)
    float* naout = out + BSS;    // neibor_attn output

    // workspace layout (~39 MB)
    char* ws = (char*)d_ws;
    short*  xb    = (short*)(ws);                        // 16 MB  x (bf16)
    short*  wqt   = (short*)(ws + (16ull << 20));        //  2 MB  Wq^T (bf16)
    short*  wkt   = (short*)(ws + (18ull << 20));        //  2 MB  Wk^T (bf16)
    short*  m2t   = (short*)(ws + (20ull << 20));        //  2 MB  (Wq^T Wk)^T
    short*  tb    = (short*)(ws + (22ull << 20));        // 16 MB  t = x@M2
    float*  m2par = (float*)tb;                          // 16 MB  split-K partials (aliased)
    double* cumd  = (double*)(ws + (38ull << 20));       // 64 KB
    float*  uvec  = (float*)(ws + (38ull << 20) + (1ull << 16)); // 4 KB
    float*  vvec  = uvec + 1024;                         // 4 KB
    float*  c0    = vvec + 1024;                         // 4 B (padded)
    float*  pvec  = c0 + 64;                             // 32 KB (8192 f32)
    float*  rvec  = pvec + 8192;                         // 32 KB
    float*  pu    = rvec + 8192;                         // 64 KB (16x1024)
    float*  pv    = pu + 16384;                          // 64 KB
    float2* statv = (float2*)(pv + 16384);               // 64 KB (8192 float2)

    bias_gemv1<<<dim3(8, 16), 256, 0, stream>>>(Wq, Wk, bk, bq, pu, pv);
    bias_gemv2<<<4, 256, 0, stream>>>(pu, pv, bk, bq, uvec, vvec, c0);
    ln_kernel<<<8192, 256, 0, stream>>>(context, gamma, beta, uvec, vvec,
                                        xb, pvec, rvec);
    cvt_t_kernel<<<dim3(32, 32, 2), 256, 0, stream>>>(Wq, Wk, wqt, wkt);
    gemm_splitk<<<dim3(4, 4, 4), 512, 0, stream>>>(wkt, wqt, m2par);
    reduce_m2t<<<1024, 256, 0, stream>>>(m2par, m2t);
    gemm_bf16<<<dim3(32, 4), 512, 0, stream>>>(xb, m2t, tb);
    gemm_scores<<<dim3(4, 4, 8), 512, 0, stream>>>(tb, xb, pvec, rvec, c0,
                                                   adj, gout);
    rowstat_kernel<<<8192, 256, 0, stream>>>(gout, statv);
    cum2_kernel<<<8, 1024, 0, stream>>>(gout, statv, prior, cumd);
    na_g2_kernel<<<dim3(1024, 8), 256, 0, stream>>>(gout, statv, prior, cumd,
                                                    naout);
}

// Round 12
// 120.777 us; speedup vs baseline: 1.3555x; 1.3555x over previous
//
#include <hip/hip_runtime.h>
#include <hip/hip_bf16.h>

// Shapes (fixed for this problem)
#define S_LEN 1024
#define D_DIM 1024
#define N_BAT 8
#define BSS   (8ull*1024ull*1024ull)   // B*S*S elements per output

using bf16x8 = __attribute__((ext_vector_type(8))) short;
using f32x4  = __attribute__((ext_vector_type(4))) float;

__device__ __forceinline__ short f2bf(float v) {
    __hip_bfloat16 h = __float2bfloat16(v);
    return *reinterpret_cast<short*>(&h);
}

__device__ __forceinline__ void gload_lds16(const void* g, void* l) {
    __builtin_amdgcn_global_load_lds(
        (const __attribute__((address_space(1))) void*)g,
        (__attribute__((address_space(3))) void*)l, 16, 0, 0);
}

// ---------------------------------------------------------------------------
// 256x128-tile GEMM mainloop, BK=64, 8 waves (512 thr), wave tile 64x64,
// ring-3 LDS (A 3x32KB + B 3x16KB = 144KB). R12: software-pipelined frag
// reads — iter t does {stage(t+2) | vmcnt(6) | lgkmcnt(0) | barrier |
// ds_read frags(t+1) || MFMA(t)}. Reads and MFMAs are register-independent
// -> overlap. lgkmcnt(0) BEFORE the barrier guarantees all waves' reads of
// the recycled ring slot are complete before stage(t+2) overwrites it.
// T2 XOR swizzle (pre-swizzled global source, same XOR on ds_read; verified
// 0 bank conflicts R6-R11). T5 setprio around MFMA cluster.
// ---------------------------------------------------------------------------
#define RDFRAG(slot, AF, BF)                                                  \
    {                                                                         \
        const char* _Ac = (const char*)As + (slot) * 32768;                   \
        const char* _Bc = (const char*)Bs + (slot) * 16384;                   \
        _Pragma("unroll")                                                     \
        for (int _m = 0; _m < 4; ++_m) {                                      \
            const int _row = wr * 64 + _m * 16 + rsel;                        \
            _Pragma("unroll")                                                 \
            for (int _kk = 0; _kk < 2; ++_kk)                                 \
                AF[_m][_kk] = *(const bf16x8*)&_Ac[_row * 128 +               \
                                                  ((_kk * 64 + kb) ^ sw)];    \
        }                                                                     \
        _Pragma("unroll")                                                     \
        for (int _n = 0; _n < 4; ++_n) {                                      \
            const int _row = wc * 64 + _n * 16 + rsel;                        \
            _Pragma("unroll")                                                 \
            for (int _kk = 0; _kk < 2; ++_kk)                                 \
                BF[_n][_kk] = *(const bf16x8*)&_Bc[_row * 128 +               \
                                                  ((_kk * 64 + kb) ^ sw)];    \
        }                                                                     \
    }

#define MMA_ALL(AF, BF)                                                       \
    __builtin_amdgcn_s_setprio(1);                                            \
    _Pragma("unroll")                                                         \
    for (int _kk = 0; _kk < 2; ++_kk)                                         \
        _Pragma("unroll")                                                     \
        for (int _m = 0; _m < 4; ++_m)                                        \
            _Pragma("unroll")                                                  \
            for (int _n = 0; _n < 4; ++_n)                                    \
                acc[_m][_n] = __builtin_amdgcn_mfma_f32_16x16x32_bf16(        \
                    AF[_m][_kk], BF[_n][_kk], acc[_m][_n], 0, 0, 0);          \
    __builtin_amdgcn_s_setprio(0);

template<int KITERS>
__device__ __forceinline__ void gemm_mainloop256(
    const short* __restrict__ A, const short* __restrict__ Bt,
    int brow, int bcol, int kstart,
    short* As, short* Bs, f32x4 acc[4][4])
{
    const int tid  = threadIdx.x;
    const int lane = tid & 63;
    const int w    = tid >> 6;
    const int wr   = w >> 1;            // 0..3
    const int wc   = w & 1;             // 0..1
    const int rsel = lane & 15;
    const int kb   = (lane >> 4) * 16;
    const int sw   = (rsel & 7) << 4;

    const int srow  = tid >> 3;                              // 0..63
    const int scolb = ((tid & 7) * 16) ^ ((srow & 7) << 4);  // swizzled src byte
    const int sdst  = tid * 16;                              // linear LDS dest

#pragma unroll
    for (int m = 0; m < 4; ++m)
#pragma unroll
        for (int n = 0; n < 4; ++n) acc[m][n] = 0.0f;

    auto stage = [&](int slot, int k0) {
        char* Ad = (char*)As + slot * 32768;
        char* Bd = (char*)Bs + slot * 16384;
#pragma unroll
        for (int c = 0; c < 4; ++c) {
            const int row = c * 64 + srow;
            gload_lds16((const char*)(A + (size_t)(brow + row) * 1024 + k0) + scolb,
                        Ad + c * 8192 + sdst);
        }
#pragma unroll
        for (int c = 0; c < 2; ++c) {
            const int row = c * 64 + srow;
            gload_lds16((const char*)(Bt + (size_t)(bcol + row) * 1024 + k0) + scolb,
                        Bd + c * 8192 + sdst);
        }
    };

    // prologue: tiles 0,1 into ring slots 0,1; wait tile 0; read frags(0)
    stage(0, kstart);
    if (KITERS > 1) {
        stage(1, kstart + 64);
        asm volatile("s_waitcnt vmcnt(6)" ::: "memory");
    } else {
        asm volatile("s_waitcnt vmcnt(0)" ::: "memory");
    }
    __builtin_amdgcn_s_barrier();
    asm volatile("" ::: "memory");

    bf16x8 af0[4][2], bf0[4][2], af1[4][2], bf1[4][2];
    RDFRAG(0, af0, bf0);

#pragma unroll
    for (int t = 0; t < KITERS; ++t) {
        if (t + 2 < KITERS) stage((t + 2) % 3, kstart + (t + 2) * 64);
        if (t + 2 < KITERS)      asm volatile("s_waitcnt vmcnt(6)" ::: "memory");
        else if (t + 1 < KITERS) asm volatile("s_waitcnt vmcnt(0)" ::: "memory");
        if (t + 1 < KITERS) {
            // all our ds_reads (issued <= iter t-1) must complete before any
            // wave can overwrite the recycled slot; then publish tile t+1.
            asm volatile("s_waitcnt lgkmcnt(0)" ::: "memory");
            __builtin_amdgcn_s_barrier();
            asm volatile("" ::: "memory");
            if ((t & 1) == 0) { RDFRAG((t + 1) % 3, af1, bf1); }
            else              { RDFRAG((t + 1) % 3, af0, bf0); }
        }
        if ((t & 1) == 0) { MMA_ALL(af0, bf0); }
        else              { MMA_ALL(af1, bf1); }
    }
}

// ---------------------------------------------------------------------------
// 3a) bf16-out GEMM for t = xb @ m2t^T. Grid (32, 8) = 256 blocks = 1/CU.
//     XCD map: 4 A-row-panels x all 8 cols per XCD (2MB A + 2MB B in L2).
// ---------------------------------------------------------------------------
__global__ __launch_bounds__(512) void gemm_bf16(
    const short* __restrict__ A, const short* __restrict__ Bt,
    short* __restrict__ C)
{
    __shared__ short As[3 * 16384];
    __shared__ short Bs[3 * 8192];
    const int flat = blockIdx.x + 32 * blockIdx.y;
    const int nid  = (flat & 7) * 32 + (flat >> 3);
    const int mx   = nid >> 3;          // 0..31
    const int ny   = nid & 7;           // 0..7
    const int brow = mx * 256, bcol = ny * 128;

    f32x4 acc[4][4];
    gemm_mainloop256<16>(A, Bt, brow, bcol, 0, As, Bs, acc);

    const int lane = threadIdx.x & 63;
    const int w    = threadIdx.x >> 6;
    const int wr   = w >> 1, wc = w & 1;
#pragma unroll
    for (int m = 0; m < 4; ++m)
#pragma unroll
        for (int n = 0; n < 4; ++n) {
            const int colg = bcol + wc * 64 + n * 16 + (lane & 15);
#pragma unroll
            for (int r = 0; r < 4; ++r) {
                const int rowg = brow + wr * 64 + m * 16 + ((lane >> 4) * 4 + r);
                C[(size_t)rowg * 1024 + colg] = f2bf(acc[m][n][r]);
            }
        }
}

// ---------------------------------------------------------------------------
// 3b) Scores GEMM + mask epilogue:
//     Sc[b][q][k] = adj ? (t[q].x[k] + p[q] + r[k] + c0)/512 : -1e9
//     Grid (4,8,8) = 256 blocks; one batch per XCD (4MB in L2).
// ---------------------------------------------------------------------------
__global__ __launch_bounds__(512) void gemm_scores(
    const short* __restrict__ Tm, const short* __restrict__ Xm,
    const float* __restrict__ p, const float* __restrict__ r2,
    const float* __restrict__ c0p, const int* __restrict__ adj,
    float* __restrict__ Sc)
{
    __shared__ short As[3 * 16384];
    __shared__ short Bs[3 * 8192];
    const int flat = blockIdx.x + 4 * blockIdx.y + 32 * blockIdx.z;
    const int nid  = (flat & 7) * 32 + (flat >> 3);
    const int b    = nid >> 5;
    const int rem  = nid & 31;
    const int mx   = rem & 3;
    const int ny   = rem >> 2;
    const short* A  = Tm + (size_t)b * 1024 * 1024;
    const short* Bt = Xm + (size_t)b * 1024 * 1024;
    const float* pb = p  + (size_t)b * 1024;
    const float* rb = r2 + (size_t)b * 1024;
    const int*   ab = adj + (size_t)b * 1024 * 1024;
    float* C = Sc + (size_t)b * 1024 * 1024;
    const int brow = mx * 256, bcol = ny * 128;

    f32x4 acc[4][4];
    gemm_mainloop256<16>(A, Bt, brow, bcol, 0, As, Bs, acc);

    const int lane = threadIdx.x & 63;
    const int w    = threadIdx.x >> 6;
    const int wr   = w >> 1, wc = w & 1;
    const float c0v = c0p[0];
#pragma unroll
    for (int m = 0; m < 4; ++m)
#pragma unroll
        for (int n = 0; n < 4; ++n) {
            const int colg = bcol + wc * 64 + n * 16 + (lane & 15);
            const float radd = rb[colg] + c0v;
#pragma unroll
            for (int r = 0; r < 4; ++r) {
                const int rowg = brow + wr * 64 + m * 16 + ((lane >> 4) * 4 + r);
                const size_t idx = (size_t)rowg * 1024 + colg;
                const float val = (acc[m][n][r] + pb[rowg] + radd) * 0.001953125f;
                C[idx] = ab[idx] ? val : -1e9f;
            }
        }
}

// ---------------------------------------------------------------------------
// 3c) M2T split-K GEMM (grid (4,8,4), KITERS=4)
// ---------------------------------------------------------------------------
__global__ __launch_bounds__(512) void gemm_splitk(
    const short* __restrict__ A, const short* __restrict__ Bt,
    float* __restrict__ P)
{
    __shared__ short As[3 * 16384];
    __shared__ short Bs[3 * 8192];
    const int brow = blockIdx.x * 256, bcol = blockIdx.y * 128;
    const int z = blockIdx.z;

    f32x4 acc[4][4];
    gemm_mainloop256<4>(A, Bt, brow, bcol, z * 256, As, Bs, acc);

    float* Pz = P + (size_t)z * 1024 * 1024;
    const int lane = threadIdx.x & 63;
    const int w    = threadIdx.x >> 6;
    const int wr   = w >> 1, wc = w & 1;
#pragma unroll
    for (int m = 0; m < 4; ++m)
#pragma unroll
        for (int n = 0; n < 4; ++n) {
            const int colg = bcol + wc * 64 + n * 16 + (lane & 15);
#pragma unroll
            for (int r = 0; r < 4; ++r) {
                const int rowg = brow + wr * 64 + m * 16 + ((lane >> 4) * 4 + r);
                Pz[(size_t)rowg * 1024 + colg] = acc[m][n][r];
            }
        }
}

// ---------------------------------------------------------------------------
// 3d) Reduce split-K partials -> bf16 m2t
// ---------------------------------------------------------------------------
__global__ __launch_bounds__(256) void reduce_m2t(
    const float* __restrict__ P, short* __restrict__ M)
{
    const int idx = blockIdx.x * 256 + threadIdx.x;
    const float4* P4 = (const float4*)P;
    float4 s = P4[idx];
    const float4 s1 = P4[idx + 262144];
    const float4 s2 = P4[idx + 524288];
    const float4 s3 = P4[idx + 786432];
    s.x += s1.x + s2.x + s3.x;
    s.y += s1.y + s2.y + s3.y;
    s.z += s1.z + s2.z + s3.z;
    s.w += s1.w + s2.w + s3.w;
    short4 o;
    o.x = f2bf(s.x); o.y = f2bf(s.y); o.z = f2bf(s.z); o.w = f2bf(s.w);
    ((short4*)M)[idx] = o;
}

// ---------------------------------------------------------------------------
// 0a/0b) Bias GEMV (unchanged)
// ---------------------------------------------------------------------------
__global__ __launch_bounds__(256) void bias_gemv1(
    const float* __restrict__ Wq, const float* __restrict__ Wk,
    const float* __restrict__ bk, const float* __restrict__ bq,
    float* __restrict__ pu, float* __restrict__ pv)
{
    __shared__ float su[8][128];
    __shared__ float sv[8][128];
    const int tx = threadIdx.x & 31;
    const int ty = threadIdx.x >> 5;
    const int colBase = blockIdx.x * 128;
    const int rowBase = blockIdx.y * 64;
    const int i = colBase + tx * 4;
    float4 au = {0,0,0,0}, av = {0,0,0,0};
#pragma unroll
    for (int jj = 0; jj < 8; ++jj) {
        const int j = rowBase + ty + jj * 8;
        const float bkv = bk[j], bqv = bq[j];
        const float4 wq = *(const float4*)&Wq[(size_t)j * 1024 + i];
        const float4 wk = *(const float4*)&Wk[(size_t)j * 1024 + i];
        au.x += wq.x * bkv; au.y += wq.y * bkv; au.z += wq.z * bkv; au.w += wq.w * bkv;
        av.x += wk.x * bqv; av.y += wk.y * bqv; av.z += wk.z * bqv; av.w += wk.w * bqv;
    }
    ((float4*)su[ty])[tx] = au;
    ((float4*)sv[ty])[tx] = av;
    __syncthreads();
    if (ty == 0) {
        float4 s1 = ((float4*)su[0])[tx];
        float4 s2 = ((float4*)sv[0])[tx];
#pragma unroll
        for (int k = 1; k < 8; ++k) {
            const float4 t1 = ((float4*)su[k])[tx];
            const float4 t2 = ((float4*)sv[k])[tx];
            s1.x += t1.x; s1.y += t1.y; s1.z += t1.z; s1.w += t1.w;
            s2.x += t2.x; s2.y += t2.y; s2.z += t2.z; s2.w += t2.w;
        }
        ((float4*)&pu[(size_t)blockIdx.y * 1024 + colBase])[tx] = s1;
        ((float4*)&pv[(size_t)blockIdx.y * 1024 + colBase])[tx] = s2;
    }
}

__global__ __launch_bounds__(256) void bias_gemv2(
    const float* __restrict__ pu, const float* __restrict__ pv,
    const float* __restrict__ bk, const float* __restrict__ bq,
    float* __restrict__ u, float* __restrict__ v, float* __restrict__ c0)
{
    __shared__ float sh[4];
    const int i = blockIdx.x * 256 + threadIdx.x;
    float su = 0.0f, sv = 0.0f;
#pragma unroll
    for (int k = 0; k < 16; ++k) {
        su += pu[k * 1024 + i];
        sv += pv[k * 1024 + i];
    }
    u[i] = su;
    v[i] = sv;
    if (blockIdx.x == 0) {
        const int t = threadIdx.x;
        const float4 a = ((const float4*)bq)[t];
        const float4 b = ((const float4*)bk)[t];
        float s = a.x*b.x + a.y*b.y + a.z*b.z + a.w*b.w;
        for (int off = 32; off > 0; off >>= 1) s += __shfl_down(s, off);
        const int lane = t & 63, w = t >> 6;
        if (lane == 0) sh[w] = s;
        __syncthreads();
        if (t == 0) c0[0] = sh[0] + sh[1] + sh[2] + sh[3];
    }
}

// ---------------------------------------------------------------------------
// 1) LayerNorm -> bf16 (unchanged)
// ---------------------------------------------------------------------------
__global__ __launch_bounds__(256) void ln_kernel(
    const float* __restrict__ X, const float* __restrict__ gamma,
    const float* __restrict__ beta, const float* __restrict__ u,
    const float* __restrict__ v2, short* __restrict__ Y,
    float* __restrict__ p, float* __restrict__ r2)
{
    __shared__ float sh[16];
    const size_t row = blockIdx.x;
    const int t = threadIdx.x;
    float4 v = ((const float4*)(X + row * 1024))[t];
    float s  = v.x + v.y + v.z + v.w;
    float ss = v.x*v.x + v.y*v.y + v.z*v.z + v.w*v.w;
    for (int off = 32; off > 0; off >>= 1) {
        s  += __shfl_down(s, off);
        ss += __shfl_down(ss, off);
    }
    const int lane = t & 63, w = t >> 6;
    if (lane == 0) { sh[w] = s; sh[4 + w] = ss; }
    __syncthreads();
    if (t == 0) {
        float S  = sh[0] + sh[1] + sh[2] + sh[3];
        float SS = sh[4] + sh[5] + sh[6] + sh[7];
        float mu = S * (1.0f / 1024.0f);
        float var = fmaxf((SS - S * mu) * (1.0f / 1023.0f), 0.0f);
        sh[0] = mu;
        sh[1] = 1.0f / (sqrtf(var) + 1e-6f);
    }
    __syncthreads();
    const float mu = sh[0], inv = sh[1];
    float4 g  = ((const float4*)gamma)[t];
    float4 be = ((const float4*)beta)[t];
    float y0 = g.x * (v.x - mu) * inv + be.x;
    float y1 = g.y * (v.y - mu) * inv + be.y;
    float y2 = g.z * (v.z - mu) * inv + be.z;
    float y3 = g.w * (v.w - mu) * inv + be.w;
    short4 o;
    o.x = f2bf(y0); o.y = f2bf(y1); o.z = f2bf(y2); o.w = f2bf(y3);
    ((short4*)(Y + row * 1024))[t] = o;
    float4 uu = ((const float4*)u)[t];
    float4 vv = ((const float4*)v2)[t];
    float dp = y0*uu.x + y1*uu.y + y2*uu.z + y3*uu.w;
    float dr = y0*vv.x + y1*vv.y + y2*vv.z + y3*vv.w;
    for (int off = 32; off > 0; off >>= 1) {
        dp += __shfl_down(dp, off);
        dr += __shfl_down(dr, off);
    }
    if (lane == 0) { sh[8 + w] = dp; sh[12 + w] = dr; }
    __syncthreads();
    if (t == 0) {
        p[row]  = sh[8] + sh[9] + sh[10] + sh[11];
        r2[row] = sh[12] + sh[13] + sh[14] + sh[15];
    }
}

// ---------------------------------------------------------------------------
// 2) Transpose + convert Wq, Wk -> bf16 transposed copies (unchanged)
// ---------------------------------------------------------------------------
__global__ __launch_bounds__(256) void cvt_t_kernel(
    const float* __restrict__ Wq, const float* __restrict__ Wk,
    short* __restrict__ wqt, short* __restrict__ wkt)
{
    __shared__ float T[32][33];
    const float* src = blockIdx.z ? Wk : Wq;
    short* dst = blockIdx.z ? wkt : wqt;
    const int bi = blockIdx.x * 32, bj = blockIdx.y * 32;
    const int c = threadIdx.x & 31, r0 = threadIdx.x >> 5;
#pragma unroll
    for (int rr = 0; rr < 4; ++rr) {
        const int r = r0 + rr * 8;
        T[r][c] = src[(size_t)(bi + r) * 1024 + bj + c];
    }
    __syncthreads();
#pragma unroll
    for (int rr = 0; rr < 4; ++rr) {
        const int r = r0 + rr * 8;
        dst[(size_t)(bj + r) * 1024 + bi + c] = f2bf(T[c][r]);
    }
}

// ---------------------------------------------------------------------------
// 5) Row stats: M = rowmax(masked scores), inv = 1/sum(exp(sc-M)).
// ---------------------------------------------------------------------------
__global__ __launch_bounds__(256) void rowstat_kernel(
    const float* __restrict__ Sc, float2* __restrict__ stats)
{
    __shared__ float sh[4];
    const size_t row = blockIdx.x;
    const int t = threadIdx.x;
    const float4 sv = ((const float4*)(Sc + row * 1024))[t];
    float m = fmaxf(fmaxf(sv.x, sv.y), fmaxf(sv.z, sv.w));
    for (int off = 32; off > 0; off >>= 1) m = fmaxf(m, __shfl_down(m, off));
    const int lane = t & 63, w = t >> 6;
    if (lane == 0) sh[w] = m;
    __syncthreads();
    const float M = fmaxf(fmaxf(sh[0], sh[1]), fmaxf(sh[2], sh[3]));
    __syncthreads();
    float s = expf(sv.x - M) + expf(sv.y - M) + expf(sv.z - M) + expf(sv.w - M);
    for (int off = 32; off > 0; off >>= 1) s += __shfl_down(s, off);
    if (lane == 0) sh[w] = s;
    __syncthreads();
    if (t == 0) {
        const float Sm = sh[0] + sh[1] + sh[2] + sh[3];
        stats[row] = make_float2(M, 1.0f / Sm);
    }
}

// ---------------------------------------------------------------------------
// 6) Prefix sums of L[k]=log(na[k,k+1]+1e-9) per batch (f64 scan in LDS)
// ---------------------------------------------------------------------------
__global__ __launch_bounds__(1024) void cum2_kernel(
    const float* __restrict__ Sc, const float2* __restrict__ stats,
    const float* __restrict__ prior_p, double* __restrict__ cum)
{
    __shared__ double sh[1024];
    const int b = blockIdx.x;
    const int t = threadIdx.x;
    const float prior = *prior_p;
    const float om = 1.0f - prior;
    const float* sc = Sc + (size_t)b * 1024 * 1024;
    const float2* st = stats + (size_t)b * 1024;
    double v = 0.0;
    if (t >= 1) {
        const int k = t - 1;
        const float2 s1 = st[k], s2 = st[k + 1];
        const float a1 = expf(sc[(size_t)k * 1024 + (k + 1)] - s1.x) * s1.y;
        const float a2 = expf(sc[(size_t)(k + 1) * 1024 + k] - s2.x) * s2.y;
        const float na = prior + om * sqrtf(a1 * a2 + 1e-9f);
        v = (double)logf(na + 1e-9f);
    }
    sh[t] = v;
    __syncthreads();
#pragma unroll
    for (int off = 1; off < 1024; off <<= 1) {
        const double add = (t >= off) ? sh[t - off] : 0.0;
        __syncthreads();
        sh[t] += add;
        __syncthreads();
    }
    cum[b * 1024 + t] = sh[t];
}

// ---------------------------------------------------------------------------
// 7) Fused softmax-finish + na + g fill (unchanged from R10)
// ---------------------------------------------------------------------------
__global__ __launch_bounds__(256) void na_g2_kernel(
    float* __restrict__ Sc, const float2* __restrict__ stats,
    const float* __restrict__ prior_p, const double* __restrict__ cum,
    float* __restrict__ NA)
{
    const int flat = blockIdx.x + 1024 * blockIdx.y;
    const int nid  = (flat & 7) * 1024 + (flat >> 3);
    const int b    = nid >> 10;
    const int tidx = nid & 1023;
    const int ti = tidx >> 5, tj = tidx & 31;
    if (tj < ti) return;
    const float prior = *prior_p;
    const float om = 1.0f - prior;
    float* sc = Sc + (size_t)b * 1024 * 1024;
    float* na = NA + (size_t)b * 1024 * 1024;
    const float2* st = stats + (size_t)b * 1024;
    const double* cb = cum + (size_t)b * 1024;
    __shared__ float T1[32][33];
    __shared__ float T2[32][33];
    const int c = threadIdx.x & 31, r0 = threadIdx.x >> 5;
#pragma unroll
    for (int rr = 0; rr < 4; ++rr) {
        const int r = r0 + rr * 8;
        const int R1 = ti * 32 + r, R2 = tj * 32 + r;
        const float2 s1 = st[R1], s2 = st[R2];
        T1[r][c] = expf(sc[(size_t)R1 * 1024 + tj * 32 + c] - s1.x) * s1.y;
        T2[r][c] = expf(sc[(size_t)R2 * 1024 + ti * 32 + c] - s2.x) * s2.y;
    }
    __syncthreads();
#pragma unroll
    for (int rr = 0; rr < 4; ++rr) {
        const int r = r0 + rr * 8;
        const int R1 = ti * 32 + r, C1 = tj * 32 + c;
        const float na1 = prior + om * sqrtf(T1[r][c] * T2[c][r] + 1e-9f);
        na[(size_t)R1 * 1024 + C1] = na1;
        float g1;
        if (R1 == C1) g1 = na1;
        else {
            const int lo = min(R1, C1), hi = max(R1, C1);
            g1 = expf((float)(cb[hi] - cb[lo])) + 1e-9f;
        }
        sc[(size_t)R1 * 1024 + C1] = g1;
        const int R2 = tj * 32 + r, C2 = ti * 32 + c;
        const float na2 = prior + om * sqrtf(T2[r][c] * T1[c][r] + 1e-9f);
        na[(size_t)R2 * 1024 + C2] = na2;
        float g2;
        if (R2 == C2) g2 = na2;
        else {
            const int lo = min(R2, C2), hi = max(R2, C2);
            g2 = expf((float)(cb[hi] - cb[lo])) + 1e-9f;
        }
        sc[(size_t)R2 * 1024 + C2] = g2;
    }
}

// ---------------------------------------------------------------------------
extern "C" void kernel_launch(void* const* d_in, const int* in_sizes, int n_in,
                              void* d_out, int out_size, void* d_ws, size_t ws_size,
                              hipStream_t stream)
{
    const float* context = (const float*)d_in[0];
    // d_in[1] = eos_mask (unused by reference)
    const float* prior   = (const float*)d_in[2];
    const int*   adj     = (const int*)d_in[3];
    const float* Wk      = (const float*)d_in[4];
    const float* bk      = (const float*)d_in[5];
    const float* Wq      = (const float*)d_in[6];
    const float* bq      = (const float*)d_in[7];
    const float* gamma   = (const float*)d_in[8];
    const float* beta    = (const float*)d_in[9];

    float* out   = (float*)d_out;
    float* gout  = out;          // g_attn output (holds masked scores first)
    float* naout = out + BSS;    // neibor_attn output

    // workspace layout (~39 MB)
    char* ws = (char*)d_ws;
    short*  xb    = (short*)(ws);                        // 16 MB  x (bf16)
    short*  wqt   = (short*)(ws + (16ull << 20));        //  2 MB  Wq^T (bf16)
    short*  wkt   = (short*)(ws + (18ull << 20));        //  2 MB  Wk^T (bf16)
    short*  m2t   = (short*)(ws + (20ull << 20));        //  2 MB  (Wq^T Wk)^T
    short*  tb    = (short*)(ws + (22ull << 20));        // 16 MB  t = x@M2
    float*  m2par = (float*)tb;                          // 16 MB  split-K partials (aliased)
    double* cumd  = (double*)(ws + (38ull << 20));       // 64 KB
    float*  uvec  = (float*)(ws + (38ull << 20) + (1ull << 16)); // 4 KB
    float*  vvec  = uvec + 1024;                         // 4 KB
    float*  c0    = vvec + 1024;                         // 4 B (padded)
    float*  pvec  = c0 + 64;                             // 32 KB (8192 f32)
    float*  rvec  = pvec + 8192;                         // 32 KB
    float*  pu    = rvec + 8192;                         // 64 KB (16x1024)
    float*  pv    = pu + 16384;                          // 64 KB
    float2* statv = (float2*)(pv + 16384);               // 64 KB (8192 float2)

    bias_gemv1<<<dim3(8, 16), 256, 0, stream>>>(Wq, Wk, bk, bq, pu, pv);
    bias_gemv2<<<4, 256, 0, stream>>>(pu, pv, bk, bq, uvec, vvec, c0);
    ln_kernel<<<8192, 256, 0, stream>>>(context, gamma, beta, uvec, vvec,
                                        xb, pvec, rvec);
    cvt_t_kernel<<<dim3(32, 32, 2), 256, 0, stream>>>(Wq, Wk, wqt, wkt);
    gemm_splitk<<<dim3(4, 8, 4), 512, 0, stream>>>(wkt, wqt, m2par);
    reduce_m2t<<<1024, 256, 0, stream>>>(m2par, m2t);
    gemm_bf16<<<dim3(32, 8), 512, 0, stream>>>(xb, m2t, tb);
    gemm_scores<<<dim3(4, 8, 8), 512, 0, stream>>>(tb, xb, pvec, rvec, c0,
                                                   adj, gout);
    rowstat_kernel<<<8192, 256, 0, stream>>>(gout, statv);
    cum2_kernel<<<8, 1024, 0, stream>>>(gout, statv, prior, cumd);
    na_g2_kernel<<<dim3(1024, 8), 256, 0, stream>>>(gout, statv, prior, cumd,
                                                    naout);
}